// Round 11
// baseline (1704.608 us; speedup 1.0000x reference)
//
#include <hip/hip_runtime.h>

#define SEQ  4096
#define HID  128
#define BT   2            // real batch columns per block (replicated into 16 MFMA cols)
#define NBLK (256 / BT)   // 128 blocks, 256 threads each -> 1 wave per SIMD

typedef int   i32x4 __attribute__((ext_vector_type(4)));
typedef float f32x4 __attribute__((ext_vector_type(4)));

#define L2E  1.44269504088896340736f   // log2(e)
#define L2E2 2.88539008177792681472f   // 2*log2(e)

__device__ __forceinline__ float exp2_(float x) { return __builtin_amdgcn_exp2f(x); }
__device__ __forceinline__ float rcp_(float x)  { return __builtin_amdgcn_rcpf(x); }
// gate pre-scaled by log2e: sigmoid(x) = 1/(1+2^-x')
__device__ __forceinline__ float sigm2(float xp) { return rcp_(1.f + exp2_(-xp)); }
// gate pre-scaled by 2*log2e: tanh(x) = 1 - 2/(1+2^x')
__device__ __forceinline__ float tanh2(float xp) { return 1.f - 2.f * rcp_(1.f + exp2_(xp)); }

// One block = 2 batch columns, 4 waves (256 thr) -> ONE wave per SIMD.
// Round 11 vs round 10 (same structure):
//  - __launch_bounds__(256,1): rounds 10's (256,2) capped VGPR at 128 and the
//    unrolled body spilled (WRITE_SIZE 40KB -> 7.3MB = scratch). We only ever
//    get 1 block/CU (128 blocks / 256 CUs), so the cap bought nothing.
//  - input projection (u-read + 12 FMAs) hoisted BEFORE the barrier: it
//    depends only on uring (stable >=4 steps ahead), shortening the
//    post-barrier chain to ds_read B -> MFMAs -> tail.
//  - B0 read issued first so the leading MFMA pair waits on a shorter lgkmcnt.
__global__ __launch_bounds__(256, 1)
void lstm_mfma(const float* __restrict__ inputs,   // (B,S,3)
               const float* __restrict__ hx0,      // (B,128)
               const float* __restrict__ cx0,      // (B,128)
               const float* __restrict__ W_inp,    // (64,3)
               const float* __restrict__ b_inp,    // (64)
               const float* __restrict__ W_ih,     // (512,64)
               const float* __restrict__ b_ih,     // (512)
               const float* __restrict__ W_hh,     // (512,128)
               const float* __restrict__ b_hh,     // (512)
               const float* __restrict__ W_out,    // (40,128)
               const float* __restrict__ b_out,    // (40)
               float*       __restrict__ out)      // (B,40)
{
    // h state (int8), double-buffered, transposed:
    // byte (kt,q,c,i) = h_q[k = kt*64 + q*16 + i][col c]
    __shared__ signed char xvT[2][2][4][2][16];   // 512 B
    // input ring (f32): slot s&15 holds {u0,u1,u2,pad} per col, filled 8+ ahead
    __shared__ float uring[16][2][4];             // 512 B
    __shared__ float hxf[BT][HID + 4];            // final fp32 hx for out-projection

    const int tid  = threadIdx.x;
    const int w    = tid >> 6;        // wave 0..3 (one per SIMD)
    const int lane = tid & 63;
    const int q    = lane >> 4;       // 0..3
    const int n    = lane & 15;
    const int bbase = blockIdx.x * BT;

    const int  cc   = n & 1;                 // lane's batch column
    const bool rb1  = (n >> 1) & 1;          // acc reg select bit 0
    const bool rb2  = (n >> 2) & 1;          // acc reg select bit 1
    const bool hi8  = (n >> 3) & 1;          // M-subtile select
    const int  rr   = (n >> 1) & 3;
    const int  hrow = w * 16 + (hi8 ? 64 : 0) + q * 4 + rr;  // lane's hidden row

    // ---- A fragments: int8, per-row symmetric scale, 2 M-subtiles per gate ------
    // Lane (q,n), gate t, subtile s, K-tile kt holds W_hh[m][kt*64 + q*16 + i],
    // m = t*128 + (w + 4s)*16 + n. A and B share the slot->k bijection (verified).
    i32x4 A[4][2][2];
    float dq[4];                          // dequant scale for THIS lane's epilogue row
    #pragma unroll
    for (int t = 0; t < 4; ++t) {
        #pragma unroll
        for (int s = 0; s < 2; ++s) {
            const int m = t * 128 + (w + 4 * s) * 16 + n;
            const float* whr = W_hh + m * HID;
            float mx = 0.f;
            for (int k = 0; k < 128; ++k) mx = fmaxf(mx, fabsf(whr[k]));
            const float rs = (mx > 0.f) ? 127.f / mx : 0.f;
            #pragma unroll
            for (int kt = 0; kt < 2; ++kt) {
                union { signed char c[16]; i32x4 v; } pk;
                #pragma unroll
                for (int i = 0; i < 16; ++i)
                    pk.c[i] = (signed char)(int)rintf(whr[kt * 64 + q * 16 + i] * rs);
                A[t][s][kt] = pk.v;
            }
        }
        // epilogue row me = t*128 + hrow: recomputed identically by every lane
        // that touches row me (deterministic fp -> consistent with A-quant above)
        const int me = t * 128 + hrow;
        const float* whe = W_hh + me * HID;
        float mxe = 0.f;
        for (int k = 0; k < 128; ++k) mxe = fmaxf(mxe, fabsf(whe[k]));
        dq[t] = (mxe / 127.f) * (1.f / 127.f) * ((t == 2) ? L2E2 : L2E);
    }

    // ---- weff for THIS lane's epilogue row (input proj, exact f32, L2E-scaled) --
    float4 wf[4];
    #pragma unroll
    for (int t = 0; t < 4; ++t) {
        const float scl = (t == 2) ? L2E2 : L2E;
        const int m2 = t * 128 + hrow;
        const float* wir = W_ih + m2 * 64;
        float wx = 0.f, wy = 0.f, wz = 0.f, bb = 0.f;
        for (int hh = 0; hh < 64; ++hh) {
            float wv = wir[hh];
            wx += wv * W_inp[hh * 3 + 0];
            wy += wv * W_inp[hh * 3 + 1];
            wz += wv * W_inp[hh * 3 + 2];
            bb += wv * b_inp[hh];
        }
        bb += b_ih[m2] + b_hh[m2];
        wf[t] = make_float4(wx * scl, wy * scl, wz * scl, bb * scl);
    }

    // ---- Loader lane mapping (wave 1): 48 floats = 8 steps x 2 cols x 3 ---------
    const bool uldr = (w == 1) && (lane < 48);
    const int  col0 = lane / 24, rem0 = lane % 24, slot0 = rem0 / 3, wi0 = rem0 % 3;
    const float* up0 = inputs + (size_t)(bbase + col0) * (SEQ * 3) + wi0;

    // ---- Init LDS ----------------------------------------------------------------
    if (tid < 2 * 2 * 4 * 2 * 16 / 4) ((int*)xvT)[tid] = 0;
    __syncthreads();
    {   // h0 quantized (clip to [-1,1]: only perturbs step 1, damped by forget gate)
        int c = tid >> 7, h = tid & 127;
        float v = hx0[(bbase + c) * HID + h];
        v = fminf(fmaxf(v, -1.f), 1.f);
        xvT[0][h >> 6][(h >> 4) & 3][c][h & 15] = (signed char)(int)rintf(v * 127.f);
    }
    if (uldr) {   // ring slots 0..15 = steps 0..15
        uring[slot0][col0][wi0]     = up0[slot0 * 3];
        uring[8 + slot0][col0][wi0] = up0[(8 + slot0) * 3];
    }
    float creg = cx0[(bbase + cc) * HID + hrow];
    __syncthreads();

    float pend0 = 0.f, hl = 0.f;

    // prologue: input projection for step 0 (slot 0)
    float inpc[4];
    {
        const f32x4 u4 = *reinterpret_cast<const f32x4*>(&uring[0][cc][0]);
        #pragma unroll
        for (int t = 0; t < 4; ++t)
            inpc[t] = fmaf(wf[t].x, u4[0], fmaf(wf[t].y, u4[1],
                      fmaf(wf[t].z, u4[2], wf[t].w)));
    }

    // ---- Recurrent loop: 16 statically-unrolled substeps per iteration -----------
    for (int sb = 0; sb < SEQ; sb += 16) {
        #pragma unroll
        for (int j = 0; j < 16; ++j) {
            signed char (*br)[4][2][16] = xvT[j & 1];
            signed char (*bw)[4][2][16] = xvT[(j + 1) & 1];

            // deep input prefetch: issue at j=0/8 (8+ steps ahead), write at j=4/12
            if (uldr) {
                if (j == 0) {
                    int st0 = sb + 8 + slot0; if (st0 > SEQ - 1) st0 = SEQ - 1;
                    pend0 = up0[st0 * 3];
                } else if (j == 4) {        // slots 8..15 <- steps sb+8..sb+15
                    uring[8 + slot0][col0][wi0] = pend0;
                } else if (j == 8) {
                    int st0 = sb + 16 + slot0; if (st0 > SEQ - 1) st0 = SEQ - 1;
                    pend0 = up0[st0 * 3];
                } else if (j == 12) {       // slots 0..7 <- steps sb+16..sb+23
                    uring[slot0][col0][wi0] = pend0;
                }
            }

            // int8 B fragments (static offsets); B0 first -> leading MFMA pair
            // only waits on the first ds_read
            const i32x4 B0 = *reinterpret_cast<const i32x4*>(&br[0][q][cc][0]);
            const i32x4 B1 = *reinterpret_cast<const i32x4*>(&br[1][q][cc][0]);

            const i32x4 z4 = {0, 0, 0, 0};
            // per-gate: 4 MFMAs (2 subtiles x 2 K) then 1-of-8 select + activation;
            // activation VALU/TRANS hides under the next gate's MFMA drain.
            float gv4[4];
            #pragma unroll
            for (int t = 0; t < 4; ++t) {
                i32x4 a0 = __builtin_amdgcn_mfma_i32_16x16x64_i8(A[t][0][0], B0, z4, 0, 0, 0);
                a0       = __builtin_amdgcn_mfma_i32_16x16x64_i8(A[t][0][1], B1, a0, 0, 0, 0);
                i32x4 a1 = __builtin_amdgcn_mfma_i32_16x16x64_i8(A[t][1][0], B0, z4, 0, 0, 0);
                a1       = __builtin_amdgcn_mfma_i32_16x16x64_i8(A[t][1][1], B1, a1, 0, 0, 0);
                int s0 = rb1 ? a0[1] : a0[0];
                int s1 = rb1 ? a0[3] : a0[2];
                int v0 = rb2 ? s1 : s0;
                int t0 = rb1 ? a1[1] : a1[0];
                int t1 = rb1 ? a1[3] : a1[2];
                int v1 = rb2 ? t1 : t0;
                int v  = hi8 ? v1 : v0;
                gv4[t] = (float)v * dq[t] + inpc[t];
            }

            // one LSTM update per lane (fp32 state); all exp are exp2
            float iv = sigm2(gv4[0]), fv = sigm2(gv4[1]);
            float gg = tanh2(gv4[2]), ov = sigm2(gv4[3]);
            creg = fv * creg + iv * gg;
            float th = tanh2(creg * L2E2);
            float h  = ov * th;                       // |h| < 1 by construction
            hl = h;

            bw[hi8 ? 1 : 0][w][cc][q * 4 + rr] = (signed char)(int)rintf(h * 127.f);

            // input projection for the NEXT step (slot (j+1)&15, stable since
            // >=3 barriers after its ring write; disjoint from this region's
            // uldr writes) -- off the post-barrier critical path.
            {
                const f32x4 u4 = *reinterpret_cast<const f32x4*>(&uring[(j + 1) & 15][cc][0]);
                #pragma unroll
                for (int t = 0; t < 4; ++t)
                    inpc[t] = fmaf(wf[t].x, u4[0], fmaf(wf[t].y, u4[1],
                              fmaf(wf[t].z, u4[2], wf[t].w)));
            }
            __syncthreads();
        }
    }

    // ---- Out projection: out[b] = W_out @ hx_last + b_out (f32 h, unquantized) ---
    hxf[cc][hrow] = hl;
    __syncthreads();
    if (tid < BT * 40) {
        int bl = tid / 40, o = tid % 40;
        const float* wr = W_out + o * HID;
        float a = b_out[o];
        #pragma unroll 8
        for (int k = 0; k < HID; ++k) a += wr[k] * hxf[bl][k];
        out[(bbase + bl) * 40 + o] = a;
    }
}

extern "C" void kernel_launch(void* const* d_in, const int* in_sizes, int n_in,
                              void* d_out, int out_size, void* d_ws, size_t ws_size,
                              hipStream_t stream) {
    const float* inputs = (const float*)d_in[0];
    const float* hx0    = (const float*)d_in[1];
    const float* cx0    = (const float*)d_in[2];
    const float* W_inp  = (const float*)d_in[3];
    const float* b_inp  = (const float*)d_in[4];
    const float* W_ih   = (const float*)d_in[5];
    const float* b_ih   = (const float*)d_in[6];
    const float* W_hh   = (const float*)d_in[7];
    const float* b_hh   = (const float*)d_in[8];
    const float* W_out  = (const float*)d_in[9];
    const float* b_out  = (const float*)d_in[10];
    float* out = (float*)d_out;

    lstm_mfma<<<NBLK, 256, 0, stream>>>(inputs, hx0, cx0, W_inp, b_inp, W_ih, b_ih,
                                        W_hh, b_hh, W_out, b_out, out);
}

// Round 12
// 1689.418 us; speedup vs baseline: 1.0090x; 1.0090x over previous
//
#include <hip/hip_runtime.h>

#define SEQ  4096
#define HID  128
#define BT   2            // real batch columns per block (replicated into 16 MFMA cols)
#define NBLK (256 / BT)   // 128 blocks, 256 threads each -> 1 wave per SIMD

typedef int   i32x4 __attribute__((ext_vector_type(4)));
typedef float f32x4 __attribute__((ext_vector_type(4)));

#define L2E  1.44269504088896340736f   // log2(e)
#define L2E2 2.88539008177792681472f   // 2*log2(e)

__device__ __forceinline__ float exp2_(float x) { return __builtin_amdgcn_exp2f(x); }
__device__ __forceinline__ float rcp_(float x)  { return __builtin_amdgcn_rcpf(x); }
// gate pre-scaled by log2e: sigmoid(x) = 1/(1+2^-x')
__device__ __forceinline__ float sigm2(float xp) { return rcp_(1.f + exp2_(-xp)); }
// gate pre-scaled by 2*log2e: tanh(x) = 1 - 2/(1+2^x')
__device__ __forceinline__ float tanh2(float xp) { return 1.f - 2.f * rcp_(1.f + exp2_(xp)); }

// One block = 2 batch columns, 4 waves (256 thr) -> ONE wave per SIMD.
// Round 12 = round 10's body EXACTLY (input projection back in the ds_read
// latency shadow, where it is free) + __launch_bounds__(256,1) only:
// round 10's (256,2) capped VGPR at 128 and spilled ~32 regs of loop state
// (WRITE_SIZE 40KB -> 7.3MB scratch). We only ever place 1 block/CU
// (128 blocks / 256 CUs), so occupancy-2 bought nothing.
__global__ __launch_bounds__(256, 1)
void lstm_mfma(const float* __restrict__ inputs,   // (B,S,3)
               const float* __restrict__ hx0,      // (B,128)
               const float* __restrict__ cx0,      // (B,128)
               const float* __restrict__ W_inp,    // (64,3)
               const float* __restrict__ b_inp,    // (64)
               const float* __restrict__ W_ih,     // (512,64)
               const float* __restrict__ b_ih,     // (512)
               const float* __restrict__ W_hh,     // (512,128)
               const float* __restrict__ b_hh,     // (512)
               const float* __restrict__ W_out,    // (40,128)
               const float* __restrict__ b_out,    // (40)
               float*       __restrict__ out)      // (B,40)
{
    // h state (int8), double-buffered, transposed:
    // byte (kt,q,c,i) = h_q[k = kt*64 + q*16 + i][col c]
    __shared__ signed char xvT[2][2][4][2][16];   // 512 B
    // input ring (f32): slot s&15 holds {u0,u1,u2,pad} per col, filled 8+ ahead
    __shared__ float uring[16][2][4];             // 512 B
    __shared__ float hxf[BT][HID + 4];            // final fp32 hx for out-projection

    const int tid  = threadIdx.x;
    const int w    = tid >> 6;        // wave 0..3 (one per SIMD)
    const int lane = tid & 63;
    const int q    = lane >> 4;       // 0..3
    const int n    = lane & 15;
    const int bbase = blockIdx.x * BT;

    const int  cc   = n & 1;                 // lane's batch column
    const bool rb1  = (n >> 1) & 1;          // acc reg select bit 0
    const bool rb2  = (n >> 2) & 1;          // acc reg select bit 1
    const bool hi8  = (n >> 3) & 1;          // M-subtile select
    const int  rr   = (n >> 1) & 3;
    const int  hrow = w * 16 + (hi8 ? 64 : 0) + q * 4 + rr;  // lane's hidden row

    // ---- A fragments: int8, per-row symmetric scale, 2 M-subtiles per gate ------
    // Lane (q,n), gate t, subtile s, K-tile kt holds W_hh[m][kt*64 + q*16 + i],
    // m = t*128 + (w + 4s)*16 + n. A and B share the slot->k bijection (verified).
    i32x4 A[4][2][2];
    float dq[4];                          // dequant scale for THIS lane's epilogue row
    #pragma unroll
    for (int t = 0; t < 4; ++t) {
        #pragma unroll
        for (int s = 0; s < 2; ++s) {
            const int m = t * 128 + (w + 4 * s) * 16 + n;
            const float* whr = W_hh + m * HID;
            float mx = 0.f;
            for (int k = 0; k < 128; ++k) mx = fmaxf(mx, fabsf(whr[k]));
            const float rs = (mx > 0.f) ? 127.f / mx : 0.f;
            #pragma unroll
            for (int kt = 0; kt < 2; ++kt) {
                union { signed char c[16]; i32x4 v; } pk;
                #pragma unroll
                for (int i = 0; i < 16; ++i)
                    pk.c[i] = (signed char)(int)rintf(whr[kt * 64 + q * 16 + i] * rs);
                A[t][s][kt] = pk.v;
            }
        }
        // epilogue row me = t*128 + hrow: recomputed identically by every lane
        // that touches row me (deterministic fp -> consistent with A-quant above)
        const int me = t * 128 + hrow;
        const float* whe = W_hh + me * HID;
        float mxe = 0.f;
        for (int k = 0; k < 128; ++k) mxe = fmaxf(mxe, fabsf(whe[k]));
        dq[t] = (mxe / 127.f) * (1.f / 127.f) * ((t == 2) ? L2E2 : L2E);
    }

    // ---- weff for THIS lane's epilogue row (input proj, exact f32, L2E-scaled) --
    float4 wf[4];
    #pragma unroll
    for (int t = 0; t < 4; ++t) {
        const float scl = (t == 2) ? L2E2 : L2E;
        const int m2 = t * 128 + hrow;
        const float* wir = W_ih + m2 * 64;
        float wx = 0.f, wy = 0.f, wz = 0.f, bb = 0.f;
        for (int hh = 0; hh < 64; ++hh) {
            float wv = wir[hh];
            wx += wv * W_inp[hh * 3 + 0];
            wy += wv * W_inp[hh * 3 + 1];
            wz += wv * W_inp[hh * 3 + 2];
            bb += wv * b_inp[hh];
        }
        bb += b_ih[m2] + b_hh[m2];
        wf[t] = make_float4(wx * scl, wy * scl, wz * scl, bb * scl);
    }

    // ---- Loader lane mapping (wave 1): 48 floats = 8 steps x 2 cols x 3 ---------
    const bool uldr = (w == 1) && (lane < 48);
    const int  col0 = lane / 24, rem0 = lane % 24, slot0 = rem0 / 3, wi0 = rem0 % 3;
    const float* up0 = inputs + (size_t)(bbase + col0) * (SEQ * 3) + wi0;

    // ---- Init LDS ----------------------------------------------------------------
    if (tid < 2 * 2 * 4 * 2 * 16 / 4) ((int*)xvT)[tid] = 0;
    __syncthreads();
    {   // h0 quantized (clip to [-1,1]: only perturbs step 1, damped by forget gate)
        int c = tid >> 7, h = tid & 127;
        float v = hx0[(bbase + c) * HID + h];
        v = fminf(fmaxf(v, -1.f), 1.f);
        xvT[0][h >> 6][(h >> 4) & 3][c][h & 15] = (signed char)(int)rintf(v * 127.f);
    }
    if (uldr) {   // ring slots 0..15 = steps 0..15
        uring[slot0][col0][wi0]     = up0[slot0 * 3];
        uring[8 + slot0][col0][wi0] = up0[(8 + slot0) * 3];
    }
    float creg = cx0[(bbase + cc) * HID + hrow];
    __syncthreads();

    float pend0 = 0.f, hl = 0.f;

    // ---- Recurrent loop: 16 statically-unrolled substeps per iteration -----------
    for (int sb = 0; sb < SEQ; sb += 16) {
        #pragma unroll
        for (int j = 0; j < 16; ++j) {
            signed char (*br)[4][2][16] = xvT[j & 1];
            signed char (*bw)[4][2][16] = xvT[(j + 1) & 1];

            // deep input prefetch: issue at j=0/8 (8+ steps ahead), write at j=4/12
            if (uldr) {
                if (j == 0) {
                    int st0 = sb + 8 + slot0; if (st0 > SEQ - 1) st0 = SEQ - 1;
                    pend0 = up0[st0 * 3];
                } else if (j == 4) {        // slots 8..15 <- steps sb+8..sb+15
                    uring[8 + slot0][col0][wi0] = pend0;
                } else if (j == 8) {
                    int st0 = sb + 16 + slot0; if (st0 > SEQ - 1) st0 = SEQ - 1;
                    pend0 = up0[st0 * 3];
                } else if (j == 12) {       // slots 0..7 <- steps sb+16..sb+23
                    uring[slot0][col0][wi0] = pend0;
                }
            }

            // u (f32x4 broadcast, static slot) + int8 B fragments (static offsets).
            // The inp FMAs below are independent of the B reads -> they execute in
            // the ds_read latency shadow (round 10's proven placement).
            const f32x4 u4 = *reinterpret_cast<const f32x4*>(&uring[j][cc][0]);
            const i32x4 B0 = *reinterpret_cast<const i32x4*>(&br[0][q][cc][0]);
            const i32x4 B1 = *reinterpret_cast<const i32x4*>(&br[1][q][cc][0]);

            // input projection (exact f32, independent of MFMA results)
            float inp[4];
            #pragma unroll
            for (int t = 0; t < 4; ++t)
                inp[t] = fmaf(wf[t].x, u4[0], fmaf(wf[t].y, u4[1],
                         fmaf(wf[t].z, u4[2], wf[t].w)));

            const i32x4 z4 = {0, 0, 0, 0};
            // per-gate: 4 MFMAs (2 subtiles x 2 K) then 1-of-8 select + activation;
            // activation VALU/TRANS hides under the next gate's MFMA drain.
            float gv4[4];
            #pragma unroll
            for (int t = 0; t < 4; ++t) {
                i32x4 a0 = __builtin_amdgcn_mfma_i32_16x16x64_i8(A[t][0][0], B0, z4, 0, 0, 0);
                a0       = __builtin_amdgcn_mfma_i32_16x16x64_i8(A[t][0][1], B1, a0, 0, 0, 0);
                i32x4 a1 = __builtin_amdgcn_mfma_i32_16x16x64_i8(A[t][1][0], B0, z4, 0, 0, 0);
                a1       = __builtin_amdgcn_mfma_i32_16x16x64_i8(A[t][1][1], B1, a1, 0, 0, 0);
                int s0 = rb1 ? a0[1] : a0[0];
                int s1 = rb1 ? a0[3] : a0[2];
                int v0 = rb2 ? s1 : s0;
                int t0 = rb1 ? a1[1] : a1[0];
                int t1 = rb1 ? a1[3] : a1[2];
                int v1 = rb2 ? t1 : t0;
                int v  = hi8 ? v1 : v0;
                gv4[t] = (float)v * dq[t] + inp[t];
            }

            // one LSTM update per lane (fp32 state); all exp are exp2
            float iv = sigm2(gv4[0]), fv = sigm2(gv4[1]);
            float gg = tanh2(gv4[2]), ov = sigm2(gv4[3]);
            creg = fv * creg + iv * gg;
            float th = tanh2(creg * L2E2);
            float h  = ov * th;                       // |h| < 1 by construction
            hl = h;

            bw[hi8 ? 1 : 0][w][cc][q * 4 + rr] = (signed char)(int)rintf(h * 127.f);
            __syncthreads();
        }
    }

    // ---- Out projection: out[b] = W_out @ hx_last + b_out (f32 h, unquantized) ---
    hxf[cc][hrow] = hl;
    __syncthreads();
    if (tid < BT * 40) {
        int bl = tid / 40, o = tid % 40;
        const float* wr = W_out + o * HID;
        float a = b_out[o];
        #pragma unroll 8
        for (int k = 0; k < HID; ++k) a += wr[k] * hxf[bl][k];
        out[(bbase + bl) * 40 + o] = a;
    }
}

extern "C" void kernel_launch(void* const* d_in, const int* in_sizes, int n_in,
                              void* d_out, int out_size, void* d_ws, size_t ws_size,
                              hipStream_t stream) {
    const float* inputs = (const float*)d_in[0];
    const float* hx0    = (const float*)d_in[1];
    const float* cx0    = (const float*)d_in[2];
    const float* W_inp  = (const float*)d_in[3];
    const float* b_inp  = (const float*)d_in[4];
    const float* W_ih   = (const float*)d_in[5];
    const float* b_ih   = (const float*)d_in[6];
    const float* W_hh   = (const float*)d_in[7];
    const float* b_hh   = (const float*)d_in[8];
    const float* W_out  = (const float*)d_in[9];
    const float* b_out  = (const float*)d_in[10];
    float* out = (float*)d_out;

    lstm_mfma<<<NBLK, 256, 0, stream>>>(inputs, hx0, cx0, W_inp, b_inp, W_ih, b_ih,
                                        W_hh, b_hh, W_out, b_out, out);
}

// Round 13
// 1510.901 us; speedup vs baseline: 1.1282x; 1.1182x over previous
//
#include <hip/hip_runtime.h>

#define SEQ  4096
#define HID  128
#define BT   2            // real batch columns per block (replicated into 16 MFMA cols)
#define NBLK (256 / BT)   // 128 blocks, 256 threads each -> 1 wave per SIMD

typedef int   i32x4 __attribute__((ext_vector_type(4)));
typedef float f32x4 __attribute__((ext_vector_type(4)));

#define L2E  1.44269504088896340736f   // log2(e)
#define L2E2 2.88539008177792681472f   // 2*log2(e)

__device__ __forceinline__ float exp2_(float x) { return __builtin_amdgcn_exp2f(x); }
__device__ __forceinline__ float rcp_(float x)  { return __builtin_amdgcn_rcpf(x); }
// gate pre-scaled by log2e: sigmoid(x) = 1/(1+2^-x')
__device__ __forceinline__ float sigm2(float xp) { return rcp_(1.f + exp2_(-xp)); }
// gate pre-scaled by 2*log2e: tanh(x) = 1 - 2/(1+2^x')
__device__ __forceinline__ float tanh2(float xp) { return 1.f - 2.f * rcp_(1.f + exp2_(xp)); }

// One block = 2 batch columns, 4 waves (256 thr) -> ONE wave per SIMD.
// Round 13 = round 10 (best: 1461us) with ONE change: inner unroll 16 -> 8
// with a two-phase uring base in a uniform VGPR (roff ^= 64 per outer iter).
// Rationale: rounds 11/12 proved __launch_bounds__(256,1) regresses ~230us
// via worse scheduling (VGPR 160), while round 10's spill under (256,2) was
// mostly hidden. Halving the unrolled body shrinks scheduler scope so the
// loop fits the 128-VGPR cap WITHOUT spilling, keeping (256,2) codegen.
// All LDS offsets remain base+immediate (round 8's win preserved).
__global__ __launch_bounds__(256, 2)
void lstm_mfma(const float* __restrict__ inputs,   // (B,S,3)
               const float* __restrict__ hx0,      // (B,128)
               const float* __restrict__ cx0,      // (B,128)
               const float* __restrict__ W_inp,    // (64,3)
               const float* __restrict__ b_inp,    // (64)
               const float* __restrict__ W_ih,     // (512,64)
               const float* __restrict__ b_ih,     // (512)
               const float* __restrict__ W_hh,     // (512,128)
               const float* __restrict__ b_hh,     // (512)
               const float* __restrict__ W_out,    // (40,128)
               const float* __restrict__ b_out,    // (40)
               float*       __restrict__ out)      // (B,40)
{
    // h state (int8), double-buffered, transposed:
    // byte (kt,q,c,i) = h_q[k = kt*64 + q*16 + i][col c]
    __shared__ signed char xvT[2][2][4][2][16];   // 512 B
    // input ring (f32): 2 phases x 8 slots; slot p*8+j holds u(step) per col
    __shared__ float uring[16][2][4];             // 512 B
    __shared__ float hxf[BT][HID + 4];            // final fp32 hx for out-projection

    const int tid  = threadIdx.x;
    const int w    = tid >> 6;        // wave 0..3 (one per SIMD)
    const int lane = tid & 63;
    const int q    = lane >> 4;       // 0..3
    const int n    = lane & 15;
    const int bbase = blockIdx.x * BT;

    const int  cc   = n & 1;                 // lane's batch column
    const bool rb1  = (n >> 1) & 1;          // acc reg select bit 0
    const bool rb2  = (n >> 2) & 1;          // acc reg select bit 1
    const bool hi8  = (n >> 3) & 1;          // M-subtile select
    const int  rr   = (n >> 1) & 3;
    const int  hrow = w * 16 + (hi8 ? 64 : 0) + q * 4 + rr;  // lane's hidden row

    // ---- A fragments: int8, per-row symmetric scale, 2 M-subtiles per gate ------
    // Lane (q,n), gate t, subtile s, K-tile kt holds W_hh[m][kt*64 + q*16 + i],
    // m = t*128 + (w + 4s)*16 + n. A and B share the slot->k bijection (verified).
    i32x4 A[4][2][2];
    float dq[4];                          // dequant scale for THIS lane's epilogue row
    #pragma unroll
    for (int t = 0; t < 4; ++t) {
        #pragma unroll
        for (int s = 0; s < 2; ++s) {
            const int m = t * 128 + (w + 4 * s) * 16 + n;
            const float* whr = W_hh + m * HID;
            float mx = 0.f;
            for (int k = 0; k < 128; ++k) mx = fmaxf(mx, fabsf(whr[k]));
            const float rs = (mx > 0.f) ? 127.f / mx : 0.f;
            #pragma unroll
            for (int kt = 0; kt < 2; ++kt) {
                union { signed char c[16]; i32x4 v; } pk;
                #pragma unroll
                for (int i = 0; i < 16; ++i)
                    pk.c[i] = (signed char)(int)rintf(whr[kt * 64 + q * 16 + i] * rs);
                A[t][s][kt] = pk.v;
            }
        }
        // epilogue row me = t*128 + hrow: recomputed identically by every lane
        // that touches row me (deterministic fp -> consistent with A-quant above)
        const int me = t * 128 + hrow;
        const float* whe = W_hh + me * HID;
        float mxe = 0.f;
        for (int k = 0; k < 128; ++k) mxe = fmaxf(mxe, fabsf(whe[k]));
        dq[t] = (mxe / 127.f) * (1.f / 127.f) * ((t == 2) ? L2E2 : L2E);
    }

    // ---- weff for THIS lane's epilogue row (input proj, exact f32, L2E-scaled) --
    float4 wf[4];
    #pragma unroll
    for (int t = 0; t < 4; ++t) {
        const float scl = (t == 2) ? L2E2 : L2E;
        const int m2 = t * 128 + hrow;
        const float* wir = W_ih + m2 * 64;
        float wx = 0.f, wy = 0.f, wz = 0.f, bb = 0.f;
        for (int hh = 0; hh < 64; ++hh) {
            float wv = wir[hh];
            wx += wv * W_inp[hh * 3 + 0];
            wy += wv * W_inp[hh * 3 + 1];
            wz += wv * W_inp[hh * 3 + 2];
            bb += wv * b_inp[hh];
        }
        bb += b_ih[m2] + b_hh[m2];
        wf[t] = make_float4(wx * scl, wy * scl, wz * scl, bb * scl);
    }

    // ---- Loader lane mapping (wave 1): 48 lanes = 8 slots x 2 cols x 3 comps ----
    const bool uldr = (w == 1) && (lane < 48);
    const int  col0 = lane / 24, rem0 = lane % 24, slot0 = rem0 / 3, wi0 = rem0 % 3;
    const float* up0 = inputs + (size_t)(bbase + col0) * (SEQ * 3) + wi0;

    // ---- Init LDS ----------------------------------------------------------------
    if (tid < 2 * 2 * 4 * 2 * 16 / 4) ((int*)xvT)[tid] = 0;
    __syncthreads();
    {   // h0 quantized (clip to [-1,1]: only perturbs step 1, damped by forget gate)
        int c = tid >> 7, h = tid & 127;
        float v = hx0[(bbase + c) * HID + h];
        v = fminf(fmaxf(v, -1.f), 1.f);
        xvT[0][h >> 6][(h >> 4) & 3][c][h & 15] = (signed char)(int)rintf(v * 127.f);
    }
    if (uldr) {   // ring: phase-0 slots = steps 0..7, phase-1 slots = steps 8..15
        uring[slot0][col0][wi0]     = up0[slot0 * 3];
        uring[8 + slot0][col0][wi0] = up0[(8 + slot0) * 3];
    }
    float creg = cx0[(bbase + cc) * HID + hrow];
    __syncthreads();

    float pend0 = 0.f, hl = 0.f;

    // two-phase ring offset (in floats): phase block = 8 slots * 8 floats = 64
    float* const urp = &uring[0][0][0];
    int roff = 0;                      // read phase offset; write phase = roff ^ 64

    // ---- Recurrent loop: 8 statically-unrolled substeps per iteration ------------
    for (int sb = 0; sb < SEQ; sb += 8) {
        #pragma unroll
        for (int j = 0; j < 8; ++j) {
            // (sb + j) & 1 == j & 1   (sb % 8 == 0)
            signed char (*br)[4][2][16] = xvT[j & 1];
            signed char (*bw)[4][2][16] = xvT[(j + 1) & 1];

            // deep input prefetch: issue at j=0 (8 steps ahead), ring-write at j=4
            if (uldr) {
                if (j == 0) {
                    int st0 = sb + 8 + slot0; if (st0 > SEQ - 1) st0 = SEQ - 1;
                    pend0 = up0[st0 * 3];
                } else if (j == 4) {   // other phase's slot0 <- step sb+8+slot0
                    urp[(roff ^ 64) + slot0 * 8 + col0 * 4 + wi0] = pend0;
                }
            }

            // u (f32x4 broadcast, base+imm) + int8 B fragments (static offsets).
            // The inp FMAs are independent of the B reads -> execute in the
            // ds_read latency shadow (round 10's proven placement).
            const f32x4 u4 = *reinterpret_cast<const f32x4*>(urp + roff + j * 8 + cc * 4);
            const i32x4 B0 = *reinterpret_cast<const i32x4*>(&br[0][q][cc][0]);
            const i32x4 B1 = *reinterpret_cast<const i32x4*>(&br[1][q][cc][0]);

            // input projection (exact f32, independent of MFMA results)
            float inp[4];
            #pragma unroll
            for (int t = 0; t < 4; ++t)
                inp[t] = fmaf(wf[t].x, u4[0], fmaf(wf[t].y, u4[1],
                         fmaf(wf[t].z, u4[2], wf[t].w)));

            const i32x4 z4 = {0, 0, 0, 0};
            // per-gate: 4 MFMAs (2 subtiles x 2 K) then 1-of-8 select + activation;
            // activation VALU/TRANS hides under the next gate's MFMA drain.
            float gv4[4];
            #pragma unroll
            for (int t = 0; t < 4; ++t) {
                i32x4 a0 = __builtin_amdgcn_mfma_i32_16x16x64_i8(A[t][0][0], B0, z4, 0, 0, 0);
                a0       = __builtin_amdgcn_mfma_i32_16x16x64_i8(A[t][0][1], B1, a0, 0, 0, 0);
                i32x4 a1 = __builtin_amdgcn_mfma_i32_16x16x64_i8(A[t][1][0], B0, z4, 0, 0, 0);
                a1       = __builtin_amdgcn_mfma_i32_16x16x64_i8(A[t][1][1], B1, a1, 0, 0, 0);
                int s0 = rb1 ? a0[1] : a0[0];
                int s1 = rb1 ? a0[3] : a0[2];
                int v0 = rb2 ? s1 : s0;
                int t0 = rb1 ? a1[1] : a1[0];
                int t1 = rb1 ? a1[3] : a1[2];
                int v1 = rb2 ? t1 : t0;
                int v  = hi8 ? v1 : v0;
                gv4[t] = (float)v * dq[t] + inp[t];
            }

            // one LSTM update per lane (fp32 state); all exp are exp2
            float iv = sigm2(gv4[0]), fv = sigm2(gv4[1]);
            float gg = tanh2(gv4[2]), ov = sigm2(gv4[3]);
            creg = fv * creg + iv * gg;
            float th = tanh2(creg * L2E2);
            float h  = ov * th;                       // |h| < 1 by construction
            hl = h;

            bw[hi8 ? 1 : 0][w][cc][q * 4 + rr] = (signed char)(int)rintf(h * 127.f);
            __syncthreads();
        }
        roff ^= 64;   // swap ring phase (1 VALU per 8 steps)
    }

    // ---- Out projection: out[b] = W_out @ hx_last + b_out (f32 h, unquantized) ---
    hxf[cc][hrow] = hl;
    __syncthreads();
    if (tid < BT * 40) {
        int bl = tid / 40, o = tid % 40;
        const float* wr = W_out + o * HID;
        float a = b_out[o];
        #pragma unroll 8
        for (int k = 0; k < HID; ++k) a += wr[k] * hxf[bl][k];
        out[(bbase + bl) * 40 + o] = a;
    }
}

extern "C" void kernel_launch(void* const* d_in, const int* in_sizes, int n_in,
                              void* d_out, int out_size, void* d_ws, size_t ws_size,
                              hipStream_t stream) {
    const float* inputs = (const float*)d_in[0];
    const float* hx0    = (const float*)d_in[1];
    const float* cx0    = (const float*)d_in[2];
    const float* W_inp  = (const float*)d_in[3];
    const float* b_inp  = (const float*)d_in[4];
    const float* W_ih   = (const float*)d_in[5];
    const float* b_ih   = (const float*)d_in[6];
    const float* W_hh   = (const float*)d_in[7];
    const float* b_hh   = (const float*)d_in[8];
    const float* W_out  = (const float*)d_in[9];
    const float* b_out  = (const float*)d_in[10];
    float* out = (float*)d_out;

    lstm_mfma<<<NBLK, 256, 0, stream>>>(inputs, hx0, cx0, W_inp, b_inp, W_ih, b_ih,
                                        W_hh, b_hh, W_out, b_out, out);
}